// Round 1
// baseline (262.535 us; speedup 1.0000x reference)
//
#include <hip/hip_runtime.h>
#include <stdint.h>

#define NHEADS 16
#define HDIM 64
#define WIN 33
#define PADW 16
#define BATCH 2
#define SEQ 2048
#define MROWS (BATCH*SEQ)   // 4096

using f32x4 = __attribute__((ext_vector_type(4))) float;
using bf16x8 = __attribute__((ext_vector_type(8))) short;

__device__ inline short f2bf(float f) {
    union { float f; uint32_t u; } c; c.f = f;
    uint32_t u = c.u;
    uint32_t r = (u + 0x7fffu + ((u >> 16) & 1u)) >> 16;
    return (short)(uint16_t)r;
}

// ---------------- f32 -> bf16 conversion (8 elems/thread) ----------------
__global__ void cvt_f32_bf16_k(const float* __restrict__ in, short* __restrict__ out, int n8) {
    int i = blockIdx.x * blockDim.x + threadIdx.x;
    if (i >= n8) return;
    const f32x4 v0 = *(const f32x4*)(in + (size_t)i * 8);
    const f32x4 v1 = *(const f32x4*)(in + (size_t)i * 8 + 4);
    bf16x8 o;
    o[0] = f2bf(v0[0]); o[1] = f2bf(v0[1]); o[2] = f2bf(v0[2]); o[3] = f2bf(v0[3]);
    o[4] = f2bf(v1[0]); o[5] = f2bf(v1[1]); o[6] = f2bf(v1[2]); o[7] = f2bf(v1[3]);
    *(bf16x8*)(out + (size_t)i * 8) = o;
}

// ---------------- GEMM: C[M,N] = A[M,K](bf16) * B[N,K]^T(bf16) + bias, f32 out
// m97 structure: 128x128 tile, BK=32, 4 waves (2x2), 16x16x32 bf16 MFMA,
// global_load_lds width=16, single LDS buffer, 2 barriers per K-step.
__global__ __launch_bounds__(256, 2)
void gemm_bt_bias_k(const short* __restrict__ A, const short* __restrict__ Bm,
                    const float* __restrict__ bias, float* __restrict__ C,
                    int M, int N, int K)
{
    __shared__ short As[128 * 32];
    __shared__ short Bs[128 * 32];
    const int tid  = threadIdx.x;
    const int wave = tid >> 6;
    const int lane = tid & 63;
    const int ntn  = N >> 7;
    const int tm   = (blockIdx.x / ntn) << 7;
    const int tn   = (blockIdx.x % ntn) << 7;
    const int wr   = wave >> 1, wc = wave & 1;

    f32x4 acc[4][4];
#pragma unroll
    for (int i = 0; i < 4; ++i)
#pragma unroll
        for (int j = 0; j < 4; ++j) acc[i][j] = (f32x4)0.f;

    // staging: tile is 128 rows x 32 cols x 2B = 8192B = 8 chunks of 1024B.
    // chunk c: rows [c*16, c*16+16); lane l -> row c*16 + (l>>2), col (l&3)*8.
    const int srow = lane >> 2;
    const int scol = (lane & 3) << 3;
    const short* Abase = A  + (size_t)tm * K;
    const short* Bbase = Bm + (size_t)tn * K;
    const int c0 = wave, c1 = wave + 4;

    const int fr = lane & 15;
    const int fk = (lane >> 4) << 3;

    for (int k0 = 0; k0 < K; k0 += 32) {
        __builtin_amdgcn_global_load_lds(
            (const __attribute__((address_space(1))) void*)(Abase + (size_t)(c0 * 16 + srow) * K + k0 + scol),
            (__attribute__((address_space(3))) void*)(As + c0 * 512), 16, 0, 0);
        __builtin_amdgcn_global_load_lds(
            (const __attribute__((address_space(1))) void*)(Abase + (size_t)(c1 * 16 + srow) * K + k0 + scol),
            (__attribute__((address_space(3))) void*)(As + c1 * 512), 16, 0, 0);
        __builtin_amdgcn_global_load_lds(
            (const __attribute__((address_space(1))) void*)(Bbase + (size_t)(c0 * 16 + srow) * K + k0 + scol),
            (__attribute__((address_space(3))) void*)(Bs + c0 * 512), 16, 0, 0);
        __builtin_amdgcn_global_load_lds(
            (const __attribute__((address_space(1))) void*)(Bbase + (size_t)(c1 * 16 + srow) * K + k0 + scol),
            (__attribute__((address_space(3))) void*)(Bs + c1 * 512), 16, 0, 0);
        __syncthreads();

        bf16x8 af[4], bfr[4];
#pragma unroll
        for (int mi = 0; mi < 4; ++mi)
            af[mi] = *(const bf16x8*)(As + (wr * 64 + mi * 16 + fr) * 32 + fk);
#pragma unroll
        for (int ni = 0; ni < 4; ++ni)
            bfr[ni] = *(const bf16x8*)(Bs + (wc * 64 + ni * 16 + fr) * 32 + fk);
#pragma unroll
        for (int mi = 0; mi < 4; ++mi)
#pragma unroll
            for (int ni = 0; ni < 4; ++ni)
                acc[mi][ni] = __builtin_amdgcn_mfma_f32_16x16x32_bf16(af[mi], bfr[ni], acc[mi][ni], 0, 0, 0);
        __syncthreads();
    }

    // epilogue: C/D layout col=lane&15, row=(lane>>4)*4+reg (m89-verified)
    const int fq = lane >> 4;
#pragma unroll
    for (int mi = 0; mi < 4; ++mi) {
#pragma unroll
        for (int ni = 0; ni < 4; ++ni) {
            const int col  = tn + wc * 64 + ni * 16 + fr;
            const int row0 = tm + wr * 64 + mi * 16 + fq * 4;
            const float bv = bias[col];
#pragma unroll
            for (int r = 0; r < 4; ++r) {
                C[(size_t)(row0 + r) * N + col] = acc[mi][ni][r] + bv;
            }
        }
    }
}

// ---------------- sliding-window attention ----------------
// One thread per (b,h,s). qkv f32 layout: [b*SEQ+s][h*192 + {q:0..63, k:64..127, v:128..191}]
// Padded (out-of-range) positions contribute score=0 INSIDE softmax (reference zero-pads k),
// and zero v contribution.
__global__ __launch_bounds__(256)
void swattn_k(const float* __restrict__ qkv, short* __restrict__ ctx)
{
    const int t  = blockIdx.x * 256 + threadIdx.x;
    const int s  = t & (SEQ - 1);
    const int bh = t >> 11;            // 0..31
    const int b  = bh >> 4, h = bh & 15;
    const float* base = qkv + (size_t)b * SEQ * 3072 + h * 192;
    const float* qp   = base + (size_t)s * 3072;

    float q[64];
#pragma unroll
    for (int j = 0; j < 16; ++j) {
        f32x4 v = *(const f32x4*)(qp + j * 4);
        q[j * 4 + 0] = v[0]; q[j * 4 + 1] = v[1]; q[j * 4 + 2] = v[2]; q[j * 4 + 3] = v[3];
    }

    float sc[WIN];
#pragma unroll
    for (int w = 0; w < WIN; ++w) {
        const int p  = s + w - PADW;
        const bool ok = (p >= 0) && (p < SEQ);
        const int pc = ok ? p : (p < 0 ? 0 : SEQ - 1);
        const float* kp = base + (size_t)pc * 3072 + 64;
        float dot = 0.f;
#pragma unroll
        for (int j = 0; j < 16; ++j) {
            f32x4 v = *(const f32x4*)(kp + j * 4);
            dot += q[j * 4 + 0] * v[0] + q[j * 4 + 1] * v[1] + q[j * 4 + 2] * v[2] + q[j * 4 + 3] * v[3];
        }
        sc[w] = ok ? dot * 0.125f : 0.f;
    }

    float mx = sc[0];
#pragma unroll
    for (int w = 1; w < WIN; ++w) mx = fmaxf(mx, sc[w]);
    float sum = 0.f;
#pragma unroll
    for (int w = 0; w < WIN; ++w) { sc[w] = __expf(sc[w] - mx); sum += sc[w]; }
    const float inv = 1.f / sum;

    float o[64];
#pragma unroll
    for (int d = 0; d < 64; ++d) o[d] = 0.f;
#pragma unroll
    for (int w = 0; w < WIN; ++w) {
        const int p  = s + w - PADW;
        const bool ok = (p >= 0) && (p < SEQ);
        const int pc = ok ? p : (p < 0 ? 0 : SEQ - 1);
        const float wgt = ok ? sc[w] * inv : 0.f;
        const float* vp = base + (size_t)pc * 3072 + 128;
#pragma unroll
        for (int j = 0; j < 16; ++j) {
            f32x4 v = *(const f32x4*)(vp + j * 4);
            o[j * 4 + 0] += wgt * v[0]; o[j * 4 + 1] += wgt * v[1];
            o[j * 4 + 2] += wgt * v[2]; o[j * 4 + 3] += wgt * v[3];
        }
    }

    // ctx layout: [b*SEQ+s][h*64 + d]  (bf16, feeds output GEMM as A)
    short* cp = ctx + (size_t)(b * SEQ + s) * 1024 + h * 64;
#pragma unroll
    for (int j = 0; j < 8; ++j) {
        bf16x8 pk;
#pragma unroll
        for (int e = 0; e < 8; ++e) pk[e] = f2bf(o[j * 8 + e]);
        *(bf16x8*)(cp + j * 8) = pk;
    }
}

// ---------------- launch ----------------
extern "C" void kernel_launch(void* const* d_in, const int* in_sizes, int n_in,
                              void* d_out, int out_size, void* d_ws, size_t ws_size,
                              hipStream_t stream)
{
    const float* x     = (const float*)d_in[0];
    const float* w_qkv = (const float*)d_in[1];
    const float* b_qkv = (const float*)d_in[2];
    const float* w_out = (const float*)d_in[3];
    const float* b_out = (const float*)d_in[4];
    float* out = (float*)d_out;

    char* ws = (char*)d_ws;
    short* x_bf    = (short*)(ws);                       // 4096*1024 bf16 = 8 MB
    short* wqkv_bf = (short*)(ws + (8ull  << 20));       // 3072*1024 bf16 = 6 MB
    short* wout_bf = (short*)(ws + (14ull << 20));       // 1024*1024 bf16 = 2 MB
    float* qkv     = (float*)(ws + (16ull << 20));       // 4096*3072 f32  = 48 MB
    short* ctx     = (short*)(ws + (64ull << 20));       // 4096*1024 bf16 = 8 MB

    cvt_f32_bf16_k<<<(MROWS * 1024 / 8) / 256, 256, 0, stream>>>(x, x_bf, MROWS * 1024 / 8);
    cvt_f32_bf16_k<<<(3072 * 1024 / 8) / 256, 256, 0, stream>>>(w_qkv, wqkv_bf, 3072 * 1024 / 8);
    cvt_f32_bf16_k<<<(1024 * 1024 / 8) / 256, 256, 0, stream>>>(w_out, wout_bf, 1024 * 1024 / 8);

    // qkv = x @ w_qkv^T + b_qkv  (f32 out for attention precision)
    gemm_bt_bias_k<<<dim3((MROWS / 128) * (3072 / 128)), 256, 0, stream>>>(
        x_bf, wqkv_bf, b_qkv, qkv, MROWS, 3072, 1024);

    // sliding-window attention -> ctx (bf16)
    swattn_k<<<dim3(BATCH * NHEADS * SEQ / 256), 256, 0, stream>>>(qkv, (short*)ctx);

    // out = ctx @ w_out^T + b_out (f32 to d_out)
    gemm_bt_bias_k<<<dim3((MROWS / 128) * (1024 / 128)), 256, 0, stream>>>(
        ctx, wout_bf, b_out, out, MROWS, 1024, 1024);
}

// Round 2
// 141.409 us; speedup vs baseline: 1.8566x; 1.8566x over previous
//
#include <hip/hip_runtime.h>
#include <stdint.h>

#define NHEADS 16
#define HDIM 64
#define WIN 33
#define PADW 16
#define BATCH 2
#define SEQ 2048
#define MROWS (BATCH*SEQ)   // 4096

#define TS 64               // seq positions per attention block
#define HALO 16
#define NPOS (TS + 2*HALO)  // 96 staged positions

using f32x4 = __attribute__((ext_vector_type(4))) float;
using bf16x8 = __attribute__((ext_vector_type(8))) short;

__device__ inline short f2bf(float f) {
    union { float f; uint32_t u; } c; c.f = f;
    uint32_t u = c.u;
    uint32_t r = (u + 0x7fffu + ((u >> 16) & 1u)) >> 16;
    return (short)(uint16_t)r;
}

// ---------------- f32 -> bf16 conversion (8 elems/thread) ----------------
__global__ void cvt_f32_bf16_k(const float* __restrict__ in, short* __restrict__ out, int n8) {
    int i = blockIdx.x * blockDim.x + threadIdx.x;
    if (i >= n8) return;
    const f32x4 v0 = *(const f32x4*)(in + (size_t)i * 8);
    const f32x4 v1 = *(const f32x4*)(in + (size_t)i * 8 + 4);
    bf16x8 o;
    o[0] = f2bf(v0[0]); o[1] = f2bf(v0[1]); o[2] = f2bf(v0[2]); o[3] = f2bf(v0[3]);
    o[4] = f2bf(v1[0]); o[5] = f2bf(v1[1]); o[6] = f2bf(v1[2]); o[7] = f2bf(v1[3]);
    *(bf16x8*)(out + (size_t)i * 8) = o;
}

// ---------------- GEMM: C[M,N] = A[M,K](bf16) * B[N,K]^T(bf16) + bias, f32 out
// m97 structure: 128x128 tile, BK=32, 4 waves (2x2), 16x16x32 bf16 MFMA.
__global__ __launch_bounds__(256, 2)
void gemm_bt_bias_k(const short* __restrict__ A, const short* __restrict__ Bm,
                    const float* __restrict__ bias, float* __restrict__ C,
                    int M, int N, int K)
{
    __shared__ short As[128 * 32];
    __shared__ short Bs[128 * 32];
    const int tid  = threadIdx.x;
    const int wave = tid >> 6;
    const int lane = tid & 63;
    const int ntn  = N >> 7;
    const int tm   = (blockIdx.x / ntn) << 7;
    const int tn   = (blockIdx.x % ntn) << 7;
    const int wr   = wave >> 1, wc = wave & 1;

    f32x4 acc[4][4];
#pragma unroll
    for (int i = 0; i < 4; ++i)
#pragma unroll
        for (int j = 0; j < 4; ++j) acc[i][j] = (f32x4)0.f;

    const int srow = lane >> 2;
    const int scol = (lane & 3) << 3;
    const short* Abase = A  + (size_t)tm * K;
    const short* Bbase = Bm + (size_t)tn * K;
    const int c0 = wave, c1 = wave + 4;

    const int fr = lane & 15;
    const int fk = (lane >> 4) << 3;

    for (int k0 = 0; k0 < K; k0 += 32) {
        __builtin_amdgcn_global_load_lds(
            (const __attribute__((address_space(1))) void*)(Abase + (size_t)(c0 * 16 + srow) * K + k0 + scol),
            (__attribute__((address_space(3))) void*)(As + c0 * 512), 16, 0, 0);
        __builtin_amdgcn_global_load_lds(
            (const __attribute__((address_space(1))) void*)(Abase + (size_t)(c1 * 16 + srow) * K + k0 + scol),
            (__attribute__((address_space(3))) void*)(As + c1 * 512), 16, 0, 0);
        __builtin_amdgcn_global_load_lds(
            (const __attribute__((address_space(1))) void*)(Bbase + (size_t)(c0 * 16 + srow) * K + k0 + scol),
            (__attribute__((address_space(3))) void*)(Bs + c0 * 512), 16, 0, 0);
        __builtin_amdgcn_global_load_lds(
            (const __attribute__((address_space(1))) void*)(Bbase + (size_t)(c1 * 16 + srow) * K + k0 + scol),
            (__attribute__((address_space(3))) void*)(Bs + c1 * 512), 16, 0, 0);
        __syncthreads();

        bf16x8 af[4], bfr[4];
#pragma unroll
        for (int mi = 0; mi < 4; ++mi)
            af[mi] = *(const bf16x8*)(As + (wr * 64 + mi * 16 + fr) * 32 + fk);
#pragma unroll
        for (int ni = 0; ni < 4; ++ni)
            bfr[ni] = *(const bf16x8*)(Bs + (wc * 64 + ni * 16 + fr) * 32 + fk);
#pragma unroll
        for (int mi = 0; mi < 4; ++mi)
#pragma unroll
            for (int ni = 0; ni < 4; ++ni)
                acc[mi][ni] = __builtin_amdgcn_mfma_f32_16x16x32_bf16(af[mi], bfr[ni], acc[mi][ni], 0, 0, 0);
        __syncthreads();
    }

    const int fq = lane >> 4;
#pragma unroll
    for (int mi = 0; mi < 4; ++mi) {
#pragma unroll
        for (int ni = 0; ni < 4; ++ni) {
            const int col  = tn + wc * 64 + ni * 16 + fr;
            const int row0 = tm + wr * 64 + mi * 16 + fq * 4;
            const float bv = bias[col];
#pragma unroll
            for (int r = 0; r < 4; ++r) {
                C[(size_t)(row0 + r) * N + col] = acc[mi][ni][r] + bv;
            }
        }
    }
}

// ---------------- sliding-window attention, LDS-staged ----------------
// One block = one (b,h) x 64-position tile. 4 lanes per position, 16 dims/lane.
// K/V staged in LDS with 16B-slot XOR swizzle (slot ^= row&15) -> even bank-group
// spread on both the staging writes and the column-slice reads.
// Out-of-range rows zero-filled == reference's zero-pad softmax semantics.
__global__ __launch_bounds__(256, 3)
void swattn2_k(const float* __restrict__ qkv, short* __restrict__ ctx)
{
    __shared__ float Ks[NPOS * 64];
    __shared__ float Vs[NPOS * 64];
    const int tid  = threadIdx.x;
    const int tile = blockIdx.x & 31;          // SEQ/TS = 32 tiles
    const int bh   = blockIdx.x >> 5;          // 0..31
    const int b    = bh >> 4, h = bh & 15;
    const int s0   = tile * TS;
    const float* base = qkv + (size_t)b * SEQ * 3072 + h * 192;

    // stage K,V: NPOS*64 floats each = 1536 f32x4 apiece; 6 iters of 256 threads
#pragma unroll
    for (int c = 0; c < 6; ++c) {
        const int j    = c * 256 + tid;
        const int row  = j >> 4;               // 0..95
        const int col4 = j & 15;               // 16B slot within row
        const int p    = s0 - HALO + row;
        f32x4 kv = (f32x4)0.f, vv = (f32x4)0.f;
        if (p >= 0 && p < SEQ) {
            const float* rp = base + (size_t)p * 3072;
            kv = *(const f32x4*)(rp + 64  + col4 * 4);
            vv = *(const f32x4*)(rp + 128 + col4 * 4);
        }
        const int slot = col4 ^ (row & 15);
        *(f32x4*)(Ks + row * 64 + slot * 4) = kv;
        *(f32x4*)(Vs + row * 64 + slot * 4) = vv;
    }
    __syncthreads();

    const int g = tid >> 2;                    // position within tile, 0..63
    const int l = tid & 3;                     // dim quarter, 16 floats
    const int s = s0 + g;

    const float* qp = base + (size_t)s * 3072 + l * 16;
    f32x4 qf[4];
#pragma unroll
    for (int j4 = 0; j4 < 4; ++j4) qf[j4] = *(const f32x4*)(qp + j4 * 4);

    float sc[WIN];
#pragma unroll
    for (int w = 0; w < WIN; ++w) {
        const int row = g + w;
        const float* rb = Ks + row * 64;
        const int sw = row & 15;
        float d = 0.f;
#pragma unroll
        for (int j4 = 0; j4 < 4; ++j4) {
            const f32x4 kv = *(const f32x4*)(rb + (((l << 2) | j4) ^ sw) * 4);
            d += qf[j4][0]*kv[0] + qf[j4][1]*kv[1] + qf[j4][2]*kv[2] + qf[j4][3]*kv[3];
        }
        d += __shfl_xor(d, 1);
        d += __shfl_xor(d, 2);
        sc[w] = d * 0.125f;
    }

    float mx = sc[0];
#pragma unroll
    for (int w = 1; w < WIN; ++w) mx = fmaxf(mx, sc[w]);
    float sum = 0.f;
#pragma unroll
    for (int w = 0; w < WIN; ++w) { sc[w] = __expf(sc[w] - mx); sum += sc[w]; }
    const float inv = 1.f / sum;

    f32x4 of[4];
#pragma unroll
    for (int j4 = 0; j4 < 4; ++j4) of[j4] = (f32x4)0.f;
#pragma unroll
    for (int w = 0; w < WIN; ++w) {
        const int row = g + w;
        const float* rb = Vs + row * 64;
        const int sw = row & 15;
        const float wgt = sc[w];
#pragma unroll
        for (int j4 = 0; j4 < 4; ++j4) {
            const f32x4 vv = *(const f32x4*)(rb + (((l << 2) | j4) ^ sw) * 4);
            of[j4] += wgt * vv;
        }
    }
#pragma unroll
    for (int j4 = 0; j4 < 4; ++j4) of[j4] *= inv;

    // ctx layout: [b*SEQ+s][h*64 + l*16 ..] bf16
    short* cp = ctx + (size_t)(b * SEQ + s) * 1024 + h * 64 + l * 16;
    bf16x8 pk0, pk1;
#pragma unroll
    for (int e = 0; e < 4; ++e) {
        pk0[e]     = f2bf(of[0][e]);
        pk0[e + 4] = f2bf(of[1][e]);
        pk1[e]     = f2bf(of[2][e]);
        pk1[e + 4] = f2bf(of[3][e]);
    }
    *(bf16x8*)(cp)     = pk0;
    *(bf16x8*)(cp + 8) = pk1;
}

// ---------------- launch ----------------
extern "C" void kernel_launch(void* const* d_in, const int* in_sizes, int n_in,
                              void* d_out, int out_size, void* d_ws, size_t ws_size,
                              hipStream_t stream)
{
    const float* x     = (const float*)d_in[0];
    const float* w_qkv = (const float*)d_in[1];
    const float* b_qkv = (const float*)d_in[2];
    const float* w_out = (const float*)d_in[3];
    const float* b_out = (const float*)d_in[4];
    float* out = (float*)d_out;

    char* ws = (char*)d_ws;
    short* x_bf    = (short*)(ws);                       // 8 MB
    short* wqkv_bf = (short*)(ws + (8ull  << 20));       // 6 MB
    short* wout_bf = (short*)(ws + (14ull << 20));       // 2 MB
    float* qkv     = (float*)(ws + (16ull << 20));       // 48 MB
    short* ctx     = (short*)(ws + (64ull << 20));       // 8 MB

    cvt_f32_bf16_k<<<(MROWS * 1024 / 8) / 256, 256, 0, stream>>>(x, x_bf, MROWS * 1024 / 8);
    cvt_f32_bf16_k<<<(3072 * 1024 / 8) / 256, 256, 0, stream>>>(w_qkv, wqkv_bf, 3072 * 1024 / 8);
    cvt_f32_bf16_k<<<(1024 * 1024 / 8) / 256, 256, 0, stream>>>(w_out, wout_bf, 1024 * 1024 / 8);

    gemm_bt_bias_k<<<dim3((MROWS / 128) * (3072 / 128)), 256, 0, stream>>>(
        x_bf, wqkv_bf, b_qkv, qkv, MROWS, 3072, 1024);

    swattn2_k<<<dim3((SEQ / TS) * BATCH * NHEADS), 256, 0, stream>>>(qkv, (short*)ctx);

    gemm_bt_bias_k<<<dim3((MROWS / 128) * (1024 / 128)), 256, 0, stream>>>(
        ctx, wout_bf, b_out, out, MROWS, 1024, 1024);
}

// Round 3
// 122.548 us; speedup vs baseline: 2.1423x; 1.1539x over previous
//
#include <hip/hip_runtime.h>
#include <stdint.h>

#define NHEADS 16
#define HDIM 64
#define WIN 33
#define PADW 16
#define BATCH 2
#define SEQ 2048
#define MROWS (BATCH*SEQ)   // 4096

#define TS 64               // seq positions per attention block
#define HALO 16
#define NPOS (TS + 2*HALO)  // 96 staged positions
#define PARTSZ (BATCH*NHEADS*SEQ*HDIM)  // elems per q/k/v part = 4194304

using f32x4 = __attribute__((ext_vector_type(4))) float;
using bf16x8 = __attribute__((ext_vector_type(8))) short;

__device__ inline short f2bf(float f) {
    union { float f; uint32_t u; } c; c.f = f;
    uint32_t u = c.u;
    uint32_t r = (u + 0x7fffu + ((u >> 16) & 1u)) >> 16;
    return (short)(uint16_t)r;
}
__device__ inline float bf2f(short s) {
    union { uint32_t u; float f; } c; c.u = ((uint32_t)(uint16_t)s) << 16; return c.f;
}

// ---------------- f32 -> bf16 conversion (8 elems/thread) ----------------
__global__ void cvt_f32_bf16_k(const float* __restrict__ in, short* __restrict__ out, int n8) {
    int i = blockIdx.x * blockDim.x + threadIdx.x;
    if (i >= n8) return;
    const f32x4 v0 = *(const f32x4*)(in + (size_t)i * 8);
    const f32x4 v1 = *(const f32x4*)(in + (size_t)i * 8 + 4);
    bf16x8 o;
    o[0] = f2bf(v0[0]); o[1] = f2bf(v0[1]); o[2] = f2bf(v0[2]); o[3] = f2bf(v0[3]);
    o[4] = f2bf(v1[0]); o[5] = f2bf(v1[1]); o[6] = f2bf(v1[2]); o[7] = f2bf(v1[3]);
    *(bf16x8*)(out + (size_t)i * 8) = o;
}

// ---------------- GEMM (m97 structure) shared K-loop ----------------
// C = A[M,K](bf16) * B[N,K]^T(bf16), 128x128 tile, BK=32, 4 waves 2x2.
#define GEMM_KLOOP(ACC_DECL)                                                                        \
    __shared__ short As[128 * 32];                                                                  \
    __shared__ short Bs[128 * 32];                                                                  \
    const int tid  = threadIdx.x;                                                                   \
    const int wave = tid >> 6;                                                                      \
    const int lane = tid & 63;                                                                      \
    const int ntn  = N >> 7;                                                                        \
    const int tm   = (blockIdx.x / ntn) << 7;                                                       \
    const int tn   = (blockIdx.x % ntn) << 7;                                                       \
    const int wr   = wave >> 1, wc = wave & 1;                                                      \
    f32x4 acc[4][4];                                                                                \
    _Pragma("unroll") for (int i = 0; i < 4; ++i)                                                   \
        _Pragma("unroll") for (int j = 0; j < 4; ++j) acc[i][j] = (f32x4)0.f;                       \
    const int srow = lane >> 2;                                                                     \
    const int scol = (lane & 3) << 3;                                                               \
    const short* Abase = A  + (size_t)tm * K;                                                       \
    const short* Bbase = Bm + (size_t)tn * K;                                                       \
    const int c0 = wave, c1 = wave + 4;                                                             \
    const int fr = lane & 15;                                                                       \
    const int fk = (lane >> 4) << 3;                                                                \
    for (int k0 = 0; k0 < K; k0 += 32) {                                                            \
        __builtin_amdgcn_global_load_lds(                                                           \
            (const __attribute__((address_space(1))) void*)(Abase + (size_t)(c0 * 16 + srow) * K + k0 + scol), \
            (__attribute__((address_space(3))) void*)(As + c0 * 512), 16, 0, 0);                    \
        __builtin_amdgcn_global_load_lds(                                                           \
            (const __attribute__((address_space(1))) void*)(Abase + (size_t)(c1 * 16 + srow) * K + k0 + scol), \
            (__attribute__((address_space(3))) void*)(As + c1 * 512), 16, 0, 0);                    \
        __builtin_amdgcn_global_load_lds(                                                           \
            (const __attribute__((address_space(1))) void*)(Bbase + (size_t)(c0 * 16 + srow) * K + k0 + scol), \
            (__attribute__((address_space(3))) void*)(Bs + c0 * 512), 16, 0, 0);                    \
        __builtin_amdgcn_global_load_lds(                                                           \
            (const __attribute__((address_space(1))) void*)(Bbase + (size_t)(c1 * 16 + srow) * K + k0 + scol), \
            (__attribute__((address_space(3))) void*)(Bs + c1 * 512), 16, 0, 0);                    \
        __syncthreads();                                                                            \
        bf16x8 af[4], bfr[4];                                                                       \
        _Pragma("unroll") for (int mi = 0; mi < 4; ++mi)                                            \
            af[mi] = *(const bf16x8*)(As + (wr * 64 + mi * 16 + fr) * 32 + fk);                     \
        _Pragma("unroll") for (int ni = 0; ni < 4; ++ni)                                            \
            bfr[ni] = *(const bf16x8*)(Bs + (wc * 64 + ni * 16 + fr) * 32 + fk);                    \
        _Pragma("unroll") for (int mi = 0; mi < 4; ++mi)                                            \
            _Pragma("unroll") for (int ni = 0; ni < 4; ++ni)                                        \
                acc[mi][ni] = __builtin_amdgcn_mfma_f32_16x16x32_bf16(af[mi], bfr[ni], acc[mi][ni], 0, 0, 0); \
        __syncthreads();                                                                            \
    }                                                                                               \
    const int fq = lane >> 4;

// GEMM variant 1: f32 output C[M,N] + bias (for the output projection)
__global__ __launch_bounds__(256, 2)
void gemm_bt_bias_k(const short* __restrict__ A, const short* __restrict__ Bm,
                    const float* __restrict__ bias, float* __restrict__ C,
                    int M, int N, int K)
{
    GEMM_KLOOP()
#pragma unroll
    for (int mi = 0; mi < 4; ++mi) {
#pragma unroll
        for (int ni = 0; ni < 4; ++ni) {
            const int col  = tn + wc * 64 + ni * 16 + fr;
            const int row0 = tm + wr * 64 + mi * 16 + fq * 4;
            const float bv = bias[col];
#pragma unroll
            for (int r = 0; r < 4; ++r) {
                C[(size_t)(row0 + r) * N + col] = acc[mi][ni][r] + bv;
            }
        }
    }
}

// GEMM variant 2: qkv projection — bias + bf16 round + scatter to head-major
// q/k/v parts: dst[part*PARTSZ + ((b*16+h)*2048 + s)*64 + d], part = (col%192)/64.
__global__ __launch_bounds__(256, 2)
void gemm_qkv_k(const short* __restrict__ A, const short* __restrict__ Bm,
                const float* __restrict__ bias, short* __restrict__ dst,
                int M, int N, int K)
{
    GEMM_KLOOP()
#pragma unroll
    for (int mi = 0; mi < 4; ++mi) {
#pragma unroll
        for (int ni = 0; ni < 4; ++ni) {
            const int col = tn + wc * 64 + ni * 16 + fr;
            const unsigned h = (unsigned)col / 192u;
            const int c    = col - (int)h * 192;
            const int part = c >> 6;
            const int d    = c & 63;
            const int row0 = tm + wr * 64 + mi * 16 + fq * 4;
            const float bv = bias[col];
            const size_t pbase = (size_t)part * PARTSZ;
#pragma unroll
            for (int r = 0; r < 4; ++r) {
                const int row = row0 + r;                  // b*2048 + s
                const int b   = row >> 11;
                const int s   = row & 2047;
                dst[pbase + ((((size_t)b << 4) + h) << 17) + (size_t)s * 64 + d]
                    = f2bf(acc[mi][ni][r] + bv);
            }
        }
    }
}

// ---------------- sliding-window attention, bf16 head-major ----------------
// qkvb: q at 0, k at +PARTSZ, v at +2*PARTSZ, each [b][h][s][64] bf16.
// One block = one (b,h) x 64-position tile; 4 lanes/position, 16 dims/lane.
// LDS rows are 128B (8 x 16B slots); slot ^= row&7 spreads the column-slice
// reads uniformly over all 32 banks. Zero-filled halo == zero-pad softmax.
__global__ __launch_bounds__(256)
void swattn3_k(const short* __restrict__ qkvb, short* __restrict__ ctx)
{
    __shared__ short Ks[NPOS * 64];   // 12 KB
    __shared__ short Vs[NPOS * 64];   // 12 KB
    const int tid  = threadIdx.x;
    const int tile = blockIdx.x & 31;          // SEQ/TS
    const int bh   = blockIdx.x >> 5;          // 0..31
    const int b    = bh >> 4, h = bh & 15;
    const int s0   = tile * TS;
    const short* qbase = qkvb + ((size_t)bh << 17);       // bh*2048*64
    const short* kbase = qbase + PARTSZ;
    const short* vbase = qbase + 2 * PARTSZ;

    // stage K,V: 96 rows x 8 slots = 768 slot-tasks, 3 iters of 256 threads
#pragma unroll
    for (int c = 0; c < 3; ++c) {
        const int idx = c * 256 + tid;
        const int row = idx >> 3;              // 0..95
        const int sl  = idx & 7;               // 16B slot
        const int p   = s0 - HALO + row;
        bf16x8 kv = (bf16x8)0, vv = (bf16x8)0;
        if (p >= 0 && p < SEQ) {
            kv = *(const bf16x8*)(kbase + (size_t)p * 64 + sl * 8);
            vv = *(const bf16x8*)(vbase + (size_t)p * 64 + sl * 8);
        }
        const int dsti = row * 64 + ((sl ^ (row & 7)) << 3);
        *(bf16x8*)(Ks + dsti) = kv;
        *(bf16x8*)(Vs + dsti) = vv;
    }
    __syncthreads();

    const int g = tid >> 2;                    // position within tile
    const int l = tid & 3;                     // dim quarter (16 of 64)
    const int s = s0 + g;

    float qf[16];
    {
        const short* qp = qbase + (size_t)s * 64 + l * 16;
        const bf16x8 q0 = *(const bf16x8*)(qp);
        const bf16x8 q1 = *(const bf16x8*)(qp + 8);
#pragma unroll
        for (int e = 0; e < 8; ++e) { qf[e] = bf2f(q0[e]); qf[8 + e] = bf2f(q1[e]); }
    }

    float sc[WIN];
#pragma unroll
    for (int w = 0; w < WIN; ++w) {
        const int row = g + w;
        const short* rb = Ks + row * 64;
        const int sw = row & 7;
        float d = 0.f;
#pragma unroll
        for (int j8 = 0; j8 < 2; ++j8) {
            const bf16x8 kv = *(const bf16x8*)(rb + (((l << 1) | j8) ^ sw) * 8);
#pragma unroll
            for (int e = 0; e < 8; ++e) d += qf[j8 * 8 + e] * bf2f(kv[e]);
        }
        d += __shfl_xor(d, 1);
        d += __shfl_xor(d, 2);
        sc[w] = d * 0.125f;
    }

    float mx = sc[0];
#pragma unroll
    for (int w = 1; w < WIN; ++w) mx = fmaxf(mx, sc[w]);
    float sum = 0.f;
#pragma unroll
    for (int w = 0; w < WIN; ++w) { sc[w] = __expf(sc[w] - mx); sum += sc[w]; }
    const float inv = 1.f / sum;

    float of[16];
#pragma unroll
    for (int e = 0; e < 16; ++e) of[e] = 0.f;
#pragma unroll
    for (int w = 0; w < WIN; ++w) {
        const int row = g + w;
        const short* rb = Vs + row * 64;
        const int sw = row & 7;
        const float wgt = sc[w];
#pragma unroll
        for (int j8 = 0; j8 < 2; ++j8) {
            const bf16x8 vv = *(const bf16x8*)(rb + (((l << 1) | j8) ^ sw) * 8);
#pragma unroll
            for (int e = 0; e < 8; ++e) of[j8 * 8 + e] += wgt * bf2f(vv[e]);
        }
    }

    // ctx layout: [b*SEQ+s][h*64 + l*16 ..] bf16 (A-operand of out GEMM)
    short* cp = ctx + (size_t)(b * SEQ + s) * 1024 + h * 64 + l * 16;
    bf16x8 pk0, pk1;
#pragma unroll
    for (int e = 0; e < 8; ++e) {
        pk0[e] = f2bf(of[e] * inv);
        pk1[e] = f2bf(of[8 + e] * inv);
    }
    *(bf16x8*)(cp)     = pk0;
    *(bf16x8*)(cp + 8) = pk1;
}

// ---------------- launch ----------------
extern "C" void kernel_launch(void* const* d_in, const int* in_sizes, int n_in,
                              void* d_out, int out_size, void* d_ws, size_t ws_size,
                              hipStream_t stream)
{
    const float* x     = (const float*)d_in[0];
    const float* w_qkv = (const float*)d_in[1];
    const float* b_qkv = (const float*)d_in[2];
    const float* w_out = (const float*)d_in[3];
    const float* b_out = (const float*)d_in[4];
    float* out = (float*)d_out;

    char* ws = (char*)d_ws;
    short* x_bf    = (short*)(ws);                       // 8 MB
    short* wqkv_bf = (short*)(ws + (8ull  << 20));       // 6 MB
    short* wout_bf = (short*)(ws + (14ull << 20));       // 2 MB
    short* qkvb    = (short*)(ws + (16ull << 20));       // 3 x 8 MB bf16 (q,k,v head-major)
    short* ctx     = (short*)(ws + (48ull << 20));       // 8 MB

    cvt_f32_bf16_k<<<(MROWS * 1024 / 8) / 256, 256, 0, stream>>>(x, x_bf, MROWS * 1024 / 8);
    cvt_f32_bf16_k<<<(3072 * 1024 / 8) / 256, 256, 0, stream>>>(w_qkv, wqkv_bf, 3072 * 1024 / 8);
    cvt_f32_bf16_k<<<(1024 * 1024 / 8) / 256, 256, 0, stream>>>(w_out, wout_bf, 1024 * 1024 / 8);

    // qkv = x @ w_qkv^T + b_qkv -> bf16 head-major q/k/v
    gemm_qkv_k<<<dim3((MROWS / 128) * (3072 / 128)), 256, 0, stream>>>(
        x_bf, wqkv_bf, b_qkv, qkvb, MROWS, 3072, 1024);

    // sliding-window attention -> ctx (bf16)
    swattn3_k<<<dim3((SEQ / TS) * BATCH * NHEADS), 256, 0, stream>>>(qkvb, (short*)ctx);

    // out = ctx @ w_out^T + b_out (f32 to d_out)
    gemm_bt_bias_k<<<dim3((MROWS / 128) * (1024 / 128)), 256, 0, stream>>>(
        ctx, wout_bf, b_out, out, MROWS, 1024, 1024);
}

// Round 4
// 93.847 us; speedup vs baseline: 2.7975x; 1.3058x over previous
//
#include <hip/hip_runtime.h>
#include <stdint.h>

#define NHEADS 16
#define HDIM 64
#define WIN 33
#define PADW 16
#define BATCH 2
#define SEQ 2048
#define MROWS (BATCH*SEQ)   // 4096
#define PARTSZ (BATCH*NHEADS*SEQ*HDIM)  // 4194304

using f32x4 = __attribute__((ext_vector_type(4))) float;
using bf16x8 = __attribute__((ext_vector_type(8))) short;

__device__ inline short f2bf(float f) {
    union { float f; uint32_t u; } c; c.f = f;
    uint32_t u = c.u;
    uint32_t r = (u + 0x7fffu + ((u >> 16) & 1u)) >> 16;
    return (short)(uint16_t)r;
}

// ---------------- f32 -> bf16 conversion (8 elems/thread) ----------------
__global__ void cvt_f32_bf16_k(const float* __restrict__ in, short* __restrict__ out, int n8) {
    int i = blockIdx.x * blockDim.x + threadIdx.x;
    if (i >= n8) return;
    const f32x4 v0 = *(const f32x4*)(in + (size_t)i * 8);
    const f32x4 v1 = *(const f32x4*)(in + (size_t)i * 8 + 4);
    bf16x8 o;
    o[0] = f2bf(v0[0]); o[1] = f2bf(v0[1]); o[2] = f2bf(v0[2]); o[3] = f2bf(v0[3]);
    o[4] = f2bf(v1[0]); o[5] = f2bf(v1[1]); o[6] = f2bf(v1[2]); o[7] = f2bf(v1[3]);
    *(bf16x8*)(out + (size_t)i * 8) = o;
}

// ---------------- GEMM (m97 structure) shared K-loop ----------------
#define GEMM_KLOOP()                                                                                \
    __shared__ short As[128 * 32];                                                                  \
    __shared__ short Bs[128 * 32];                                                                  \
    const int tid  = threadIdx.x;                                                                   \
    const int wave = tid >> 6;                                                                      \
    const int lane = tid & 63;                                                                      \
    const int ntn  = N >> 7;                                                                        \
    const int tm   = (blockIdx.x / ntn) << 7;                                                       \
    const int tn   = (blockIdx.x % ntn) << 7;                                                       \
    const int wr   = wave >> 1, wc = wave & 1;                                                      \
    f32x4 acc[4][4];                                                                                \
    _Pragma("unroll") for (int i = 0; i < 4; ++i)                                                   \
        _Pragma("unroll") for (int j = 0; j < 4; ++j) acc[i][j] = (f32x4)0.f;                       \
    const int srow = lane >> 2;                                                                     \
    const int scol = (lane & 3) << 3;                                                               \
    const short* Abase = A  + (size_t)tm * K;                                                       \
    const short* Bbase = Bm + (size_t)tn * K;                                                       \
    const int c0 = wave, c1 = wave + 4;                                                             \
    const int fr = lane & 15;                                                                       \
    const int fk = (lane >> 4) << 3;                                                                \
    for (int k0 = 0; k0 < K; k0 += 32) {                                                            \
        __builtin_amdgcn_global_load_lds(                                                           \
            (const __attribute__((address_space(1))) void*)(Abase + (size_t)(c0 * 16 + srow) * K + k0 + scol), \
            (__attribute__((address_space(3))) void*)(As + c0 * 512), 16, 0, 0);                    \
        __builtin_amdgcn_global_load_lds(                                                           \
            (const __attribute__((address_space(1))) void*)(Abase + (size_t)(c1 * 16 + srow) * K + k0 + scol), \
            (__attribute__((address_space(3))) void*)(As + c1 * 512), 16, 0, 0);                    \
        __builtin_amdgcn_global_load_lds(                                                           \
            (const __attribute__((address_space(1))) void*)(Bbase + (size_t)(c0 * 16 + srow) * K + k0 + scol), \
            (__attribute__((address_space(3))) void*)(Bs + c0 * 512), 16, 0, 0);                    \
        __builtin_amdgcn_global_load_lds(                                                           \
            (const __attribute__((address_space(1))) void*)(Bbase + (size_t)(c1 * 16 + srow) * K + k0 + scol), \
            (__attribute__((address_space(3))) void*)(Bs + c1 * 512), 16, 0, 0);                    \
        __syncthreads();                                                                            \
        bf16x8 af[4], bfr[4];                                                                       \
        _Pragma("unroll") for (int mi = 0; mi < 4; ++mi)                                            \
            af[mi] = *(const bf16x8*)(As + (wr * 64 + mi * 16 + fr) * 32 + fk);                     \
        _Pragma("unroll") for (int ni = 0; ni < 4; ++ni)                                            \
            bfr[ni] = *(const bf16x8*)(Bs + (wc * 64 + ni * 16 + fr) * 32 + fk);                    \
        _Pragma("unroll") for (int mi = 0; mi < 4; ++mi)                                            \
            _Pragma("unroll") for (int ni = 0; ni < 4; ++ni)                                        \
                acc[mi][ni] = __builtin_amdgcn_mfma_f32_16x16x32_bf16(af[mi], bfr[ni], acc[mi][ni], 0, 0, 0); \
        __syncthreads();                                                                            \
    }                                                                                               \
    const int fq = lane >> 4;

// variant 1: f32 output + bias (output projection)
__global__ __launch_bounds__(256, 2)
void gemm_bt_bias_k(const short* __restrict__ A, const short* __restrict__ Bm,
                    const float* __restrict__ bias, float* __restrict__ C,
                    int M, int N, int K)
{
    GEMM_KLOOP()
#pragma unroll
    for (int mi = 0; mi < 4; ++mi) {
#pragma unroll
        for (int ni = 0; ni < 4; ++ni) {
            const int col  = tn + wc * 64 + ni * 16 + fr;
            const int row0 = tm + wr * 64 + mi * 16 + fq * 4;
            const float bv = bias[col];
#pragma unroll
            for (int r = 0; r < 4; ++r) {
                C[(size_t)(row0 + r) * N + col] = acc[mi][ni][r] + bv;
            }
        }
    }
}

// variant 2: qkv projection — bias + bf16 + scatter to head-major q/k and
// TRANSPOSED v: q,k at [bh][s][d]; v at [bh][d][s] (so attention can stage V^T).
__global__ __launch_bounds__(256, 2)
void gemm_qkv_k(const short* __restrict__ A, const short* __restrict__ Bm,
                const float* __restrict__ bias, short* __restrict__ dst,
                int M, int N, int K)
{
    GEMM_KLOOP()
#pragma unroll
    for (int mi = 0; mi < 4; ++mi) {
#pragma unroll
        for (int ni = 0; ni < 4; ++ni) {
            const int col = tn + wc * 64 + ni * 16 + fr;
            const unsigned h = (unsigned)col / 192u;
            const int c    = col - (int)h * 192;
            const int part = c >> 6;
            const int d    = c & 63;
            const int row0 = tm + wr * 64 + mi * 16 + fq * 4;
            const float bv = bias[col];
            const size_t pbase = (size_t)part * PARTSZ;
#pragma unroll
            for (int r = 0; r < 4; ++r) {
                const int row = row0 + r;                  // b*2048 + s
                const int b   = row >> 11;
                const int s   = row & 2047;
                const size_t hb = pbase + ((((size_t)b << 4) + h) << 17);
                const size_t addr = (part == 2)
                    ? hb + ((size_t)d << 11) + s           // v^T [d][s]
                    : hb + ((size_t)s << 6) + d;           // q,k [s][d]
                dst[addr] = f2bf(acc[mi][ni][r] + bv);
            }
        }
    }
}

// ---------------- sliding-window attention via MFMA ----------------
// Block = one (b,h) x 64-q tile, 4 waves x 16 q-rows. Swapped QK^T gives
// S^T[n][q] in-register; softmax in-register (4-lane shfl reduce); P repacked
// to A-frag layout via cvt_pk_bf16 + lane shuffles; PV uses V^T staged in LDS.
// Zero-filled out-of-seq rows reproduce zero-pad softmax semantics.
__global__ __launch_bounds__(256)
void swattn4_k(const short* __restrict__ qkvb, short* __restrict__ ctx)
{
    __shared__ short Ks[96 * 64];     // 12 KB, 16B slots XOR-swizzled by row&7
    __shared__ short Vt[64 * 104];    // 13 KB, V^T rows padded to 104 elems
    const int tid  = threadIdx.x;
    const int lane = tid & 63;
    const int w    = tid >> 6;        // wave -> q rows 16w..16w+15
    const int q15  = lane & 15;
    const int p    = lane >> 4;
    const int tile = blockIdx.x & 31;
    const int bh   = blockIdx.x >> 5;
    const int b    = bh >> 4, h = bh & 15;
    const int s0   = tile * 64;
    const short* qbase  = qkvb + ((size_t)bh << 17);
    const short* kbase  = qbase + PARTSZ;
    const short* vtbase = qbase + 2 * PARTSZ;   // [d][s]

    // stage K rows 0..95 (pos s0-16+row)
#pragma unroll
    for (int c = 0; c < 3; ++c) {
        const int idx = c * 256 + tid;
        const int row = idx >> 3;
        const int sl  = idx & 7;
        const int pos = s0 - 16 + row;
        bf16x8 kv = (bf16x8)0;
        if (pos >= 0 && pos < SEQ)
            kv = *(const bf16x8*)(kbase + (size_t)pos * 64 + sl * 8);
        *(bf16x8*)(Ks + row * 64 + ((sl ^ (row & 7)) << 3)) = kv;
    }
    // stage V^T: Vt[d][n] = v[s0-16+n][d], n in 12 slots of 8
#pragma unroll
    for (int c = 0; c < 4; ++c) {
        const int idx = c * 256 + tid;
        const int d   = idx >> 4;
        const int sl  = idx & 15;
        if (sl < 12) {
            const int pos = s0 - 16 + sl * 8;
            bf16x8 vv = (bf16x8)0;
            if (pos >= 0 && pos <= SEQ - 8)
                vv = *(const bf16x8*)(vtbase + (size_t)d * SEQ + pos);
            *(bf16x8*)(Vt + d * 104 + sl * 8) = vv;
        }
    }
    __syncthreads();

    // Q fragments from global: lane q-row = q15, k-chunk 8p (+32 for ks=1)
    const int qrow = s0 + w * 16 + q15;
    const bf16x8 qf0 = *(const bf16x8*)(qbase + (size_t)qrow * 64 + p * 8);
    const bf16x8 qf1 = *(const bf16x8*)(qbase + (size_t)qrow * 64 + 32 + p * 8);

    // QK^T (swapped): accs[t] = S^T tile t: D[n=16t+4p+r][q=q15]
    f32x4 accs[6];
#pragma unroll
    for (int t = 0; t < 6; ++t) accs[t] = (f32x4)0.f;
#pragma unroll
    for (int t = 0; t < 6; ++t) {
        const int row = t * 16 + q15;          // K-row n
        const int sw  = row & 7;
        const bf16x8 kf0 = *(const bf16x8*)(Ks + row * 64 + ((p ^ sw) << 3));
        const bf16x8 kf1 = *(const bf16x8*)(Ks + row * 64 + (((p + 4) ^ sw) << 3));
        accs[t] = __builtin_amdgcn_mfma_f32_16x16x32_bf16(kf0, qf0, accs[t], 0, 0, 0);
        accs[t] = __builtin_amdgcn_mfma_f32_16x16x32_bf16(kf1, qf1, accs[t], 0, 0, 0);
    }

    // softmax over n, window mask [qloc, qloc+32]
    const int qloc = w * 16 + q15;
    float m = -1e30f;
#pragma unroll
    for (int t = 0; t < 6; ++t)
#pragma unroll
        for (int r = 0; r < 4; ++r) {
            const int n = t * 16 + p * 4 + r;
            const bool valid = (n >= qloc) && (n <= qloc + 32);
            const float v = valid ? accs[t][r] * 0.125f : -1e30f;
            accs[t][r] = v;
            m = fmaxf(m, v);
        }
    m = fmaxf(m, __shfl_xor(m, 16));
    m = fmaxf(m, __shfl_xor(m, 32));
    float sum = 0.f;
#pragma unroll
    for (int t = 0; t < 6; ++t)
#pragma unroll
        for (int r = 0; r < 4; ++r) {
            const float e = __expf(accs[t][r] - m);
            accs[t][r] = e;
            sum += e;
        }
    sum += __shfl_xor(sum, 16);
    sum += __shfl_xor(sum, 32);
    const float inv = 1.f / sum;

    // P -> bf16 pairs (n-even in lo bits), then lane-repack to A-frag layout:
    // target (p, e, ks): n = 32ks+8p+e  <-  src lane p' = (2p+b)&3, reg (t=2ks+(p>>1), r)
    uint32_t pk[6][2];
#pragma unroll
    for (int t = 0; t < 6; ++t)
#pragma unroll
        for (int rp = 0; rp < 2; ++rp) {
            const float lo = accs[t][2 * rp] * inv;
            const float hi = accs[t][2 * rp + 1] * inv;
            uint32_t o;
            asm("v_cvt_pk_bf16_f32 %0, %1, %2" : "=v"(o) : "v"(lo), "v"(hi));
            pk[t][rp] = o;
        }
    uint32_t afu[3][4];
#pragma unroll
    for (int t = 0; t < 6; ++t)
#pragma unroll
        for (int rp = 0; rp < 2; ++rp)
#pragma unroll
            for (int bb = 0; bb < 2; ++bb) {
                const int src = q15 + (((2 * p + bb) & 3) << 4);
                const uint32_t v = __shfl((int)pk[t][rp], src);
                if ((t & 1) == (p >> 1))
                    afu[t >> 1][2 * bb + rp] = v;
            }
    union U { uint32_t u[4]; bf16x8 v; };
    U u0, u1, u2;
#pragma unroll
    for (int f = 0; f < 4; ++f) { u0.u[f] = afu[0][f]; u1.u[f] = afu[1][f]; u2.u[f] = afu[2][f]; }
    const bf16x8 af0 = u0.v, af1 = u1.v, af2 = u2.v;

    // PV: ctx[q][d] tiles; B-frag = V^T rows d, k-chunk n = 32ks+8p..+7
    f32x4 accp[4];
#pragma unroll
    for (int dt = 0; dt < 4; ++dt) accp[dt] = (f32x4)0.f;
#pragma unroll
    for (int dt = 0; dt < 4; ++dt) {
        const short* vr = Vt + (dt * 16 + q15) * 104 + p * 8;
        const bf16x8 vf0 = *(const bf16x8*)(vr);
        const bf16x8 vf1 = *(const bf16x8*)(vr + 32);
        const bf16x8 vf2 = *(const bf16x8*)(vr + 64);
        accp[dt] = __builtin_amdgcn_mfma_f32_16x16x32_bf16(af0, vf0, accp[dt], 0, 0, 0);
        accp[dt] = __builtin_amdgcn_mfma_f32_16x16x32_bf16(af1, vf1, accp[dt], 0, 0, 0);
        accp[dt] = __builtin_amdgcn_mfma_f32_16x16x32_bf16(af2, vf2, accp[dt], 0, 0, 0);
    }

    // store ctx: D col = d = 16dt+q15, row = q = 4p+r
#pragma unroll
    for (int dt = 0; dt < 4; ++dt) {
        const int d = dt * 16 + q15;
#pragma unroll
        for (int r = 0; r < 4; ++r) {
            const int s = s0 + w * 16 + p * 4 + r;
            ctx[(((size_t)(b * SEQ + s)) << 10) + h * 64 + d] = f2bf(accp[dt][r]);
        }
    }
}

// ---------------- launch ----------------
extern "C" void kernel_launch(void* const* d_in, const int* in_sizes, int n_in,
                              void* d_out, int out_size, void* d_ws, size_t ws_size,
                              hipStream_t stream)
{
    const float* x     = (const float*)d_in[0];
    const float* w_qkv = (const float*)d_in[1];
    const float* b_qkv = (const float*)d_in[2];
    const float* w_out = (const float*)d_in[3];
    const float* b_out = (const float*)d_in[4];
    float* out = (float*)d_out;

    char* ws = (char*)d_ws;
    short* x_bf    = (short*)(ws);                       // 8 MB
    short* wqkv_bf = (short*)(ws + (8ull  << 20));       // 6 MB
    short* wout_bf = (short*)(ws + (14ull << 20));       // 2 MB
    short* qkvb    = (short*)(ws + (16ull << 20));       // q,k [bh][s][d]; v^T [bh][d][s]
    short* ctx     = (short*)(ws + (48ull << 20));       // 8 MB

    cvt_f32_bf16_k<<<(MROWS * 1024 / 8) / 256, 256, 0, stream>>>(x, x_bf, MROWS * 1024 / 8);
    cvt_f32_bf16_k<<<(3072 * 1024 / 8) / 256, 256, 0, stream>>>(w_qkv, wqkv_bf, 3072 * 1024 / 8);
    cvt_f32_bf16_k<<<(1024 * 1024 / 8) / 256, 256, 0, stream>>>(w_out, wout_bf, 1024 * 1024 / 8);

    gemm_qkv_k<<<dim3((MROWS / 128) * (3072 / 128)), 256, 0, stream>>>(
        x_bf, wqkv_bf, b_qkv, qkvb, MROWS, 3072, 1024);

    swattn4_k<<<dim3((SEQ / 64) * BATCH * NHEADS), 256, 0, stream>>>(qkvb, (short*)ctx);

    gemm_bt_bias_k<<<dim3((MROWS / 128) * (1024 / 128)), 256, 0, stream>>>(
        ctx, wout_bf, b_out, out, MROWS, 1024, 1024);
}